// Round 7
// baseline (2847.936 us; speedup 1.0000x reference)
//
#include <hip/hip_runtime.h>
#include <hip/hip_bf16.h>
#include <math.h>

#define HID 256
#define BSZ 64
#define TLEN 256
#define INW 64
#define OUTW 32
#define NOISE_STD 0.05f
#define TAU 0.2f
#define NPKT 22   // ceil(64/3) packets of (3 x bf16 + 16-bit tag)

typedef __attribute__((ext_vector_type(8))) short short8;
typedef __attribute__((ext_vector_type(4))) float floatx4;
typedef unsigned long long u64;

// LDS layout for r: [b][k], 8-short-granule XOR swizzle.
// Fill (fixed b, lanes span k): all 32 banks, same-dword broadcast pairs -> conflict-free.
// A-frag b128 (8 consecutive k): uniform 8 lanes per 4-bank group -> minimum.
// Epilogue u16: 2-way with broadcast -> free.
__device__ __forceinline__ int ridx(int b, int k) {
    int P = ((b >> 2) & 7) ^ ((b & 3) << 1);
    return b * 256 + ((((k >> 3) ^ P) & 31) << 3) + (k & 7);
}

// ---------------------------------------------------------------------------
// one-time: W [j][i][k] fp32 -> bf16 in MFMA B-fragment order
//   Wsw[(((j*8+kk)*16+ni)*64+l)*8 + e] = W[j][ni*16+(l&15)][kk*32+(l>>4)*8+e]
// ---------------------------------------------------------------------------
__global__ __launch_bounds__(256) void swizzle_kernel(const float* __restrict__ W,
                                                      __hip_bfloat16* __restrict__ Wsw) {
    int g = blockIdx.x * 256 + threadIdx.x;      // 0 .. 2^21-1
    int l  = g & 63;
    int ni = (g >> 6) & 15;
    int kk = (g >> 10) & 7;
    int j  = g >> 13;
    int i  = ni * 16 + (l & 15);
    int k0 = kk * 32 + (l >> 4) * 8;
    const float* __restrict__ src = W + ((size_t)j * HID + i) * HID + k0;
    __hip_bfloat16* __restrict__ dst = Wsw + (size_t)g * 8;
#pragma unroll
    for (int e = 0; e < 8; ++e) dst[e] = __float2bfloat16(src[e]);
}

// ---------------------------------------------------------------------------
// init: buf0 packets for step 0.  packet(c,k) = r[3c..3c+2][k] | tag(=0)<<48
// grid = NPKT blocks, 256 threads (k)
// ---------------------------------------------------------------------------
__global__ __launch_bounds__(256) void init_kernel(const float* __restrict__ x0,
                                                   u64* __restrict__ buf0) {
    int c = blockIdx.x;          // 0..21
    int k = threadIdx.x;
    u64 v = 0;                   // tag field = 0
#pragma unroll
    for (int e = 0; e < 3; ++e) {
        int b = 3 * c + e;
        if (b < BSZ) {
            __hip_bfloat16 h = __float2bfloat16(tanhf(x0[b * HID + k]));
            v |= (u64)(*(unsigned short*)&h) << (16 * e);
        }
    }
    buf0[c * 256 + k] = v;
}

// ---------------------------------------------------------------------------
// one-time: pre[t][j][b] = NOISE_STD*noise[t][b][j]
//                        + TAU*(w_in_b[j] + sum_in u[b][t][in]*w_in_w[j][in])
// ---------------------------------------------------------------------------
__global__ __launch_bounds__(256) void pre_kernel(const float* __restrict__ u,
                                                  const float* __restrict__ w_in_w,
                                                  const float* __restrict__ w_in_b,
                                                  const float* __restrict__ noise,
                                                  float* __restrict__ pre) {
    __shared__ float ulds[BSZ][INW + 4];
    const int t = blockIdx.x;
    const int j = threadIdx.x;
    {
        int b = threadIdx.x >> 2, q = threadIdx.x & 3;
#pragma unroll
        for (int e = 0; e < 4; ++e) {
            float4 v = *(const float4*)(u + ((size_t)b * TLEN + t) * INW + q * 16 + e * 4);
            *(float4*)&ulds[b][q * 16 + e * 4] = v;
        }
    }
    float wreg[INW];
#pragma unroll
    for (int q = 0; q < INW / 4; ++q) {
        float4 v = *(const float4*)(w_in_w + (size_t)j * INW + q * 4);
        wreg[q * 4 + 0] = v.x; wreg[q * 4 + 1] = v.y;
        wreg[q * 4 + 2] = v.z; wreg[q * 4 + 3] = v.w;
    }
    float bias = w_in_b[j];
    __syncthreads();
    for (int b = 0; b < BSZ; ++b) {
        float s = bias;
#pragma unroll
        for (int in_ = 0; in_ < INW; ++in_) s = fmaf(ulds[b][in_], wreg[in_], s);
        float nz = noise[((size_t)t * BSZ + b) * HID + j];
        pre[((size_t)t * HID + j) * BSZ + b] = NOISE_STD * nz + TAU * s;
    }
}

// ---------------------------------------------------------------------------
// persistent kernel.  Per-step protocol (no flags, no producer drain):
//  - state exchanged as self-validating 8B packets (3 bf16 + step tag) via
//    agent-scope relaxed atomics (MALL coherence point)
//  - producer: ONE 22-lane atomic store instruction, then proceeds
//  - consumer: polls its 22 packets until all tags == t, then unpacks into
//    swizzled LDS (conflict-free column-per-thread writes)
//  - W slice lives in 128 VGPRs per lane (loaded once); LDS = 34 KB only
// ---------------------------------------------------------------------------
__global__ __launch_bounds__(256, 1) void persist_kernel(
    const __hip_bfloat16* __restrict__ Wsw,
    const float* __restrict__ w_hh,
    const float* __restrict__ u,              // fallbacks
    const float* __restrict__ w_in_w,
    const float* __restrict__ w_in_b,
    const float* __restrict__ noise,
    const float* __restrict__ x0,
    u64* __restrict__ buf0,                   // [NPKT][256] packets (t even reads)
    u64* __restrict__ buf1,                   // (t odd reads)
    float* __restrict__ traj,                 // [B][T][HID] (fallback path)
    float* __restrict__ trajWS,               // [T][HID][B] (fast path)
    float* __restrict__ xfinal,
    const float* __restrict__ pre,            // [T][HID][B] or unused
    int use_pre, int use_tws) {
    __shared__ short rlds[16384];             // 32 KB swizzled r
    __shared__ float redw[256];
    __shared__ __hip_bfloat16 exch[BSZ];

    const int tid  = threadIdx.x;
    const int j    = blockIdx.x;
    const int w    = tid >> 6;
    const int lane = tid & 63;
    const int quad = lane >> 4;
    const int col  = lane & 15;

    // ---- W B-fragments into registers: 32 x short8 = 128 VGPRs ----
    short8 wreg[32];
    {
        const short* __restrict__ wsh = (const short*)Wsw;
#pragma unroll
        for (int kk = 0; kk < 8; ++kk)
#pragma unroll
            for (int nj = 0; nj < 4; ++nj)
                wreg[kk * 4 + nj] = *(const short8*)(wsh +
                    ((((size_t)j * 8 + kk) * 16 + (w * 4 + nj)) * 64 + lane) * 8);
    }
    float whh_reg[4];
#pragma unroll
    for (int nj = 0; nj < 4; ++nj)
        whh_reg[nj] = w_hh[j * HID + (w * 4 + nj) * 16 + col];

    float xb = 0.f;
    if (tid < BSZ) xb = x0[tid * HID + j];

#pragma unroll 1
    for (int t = 0; t < TLEN; ++t) {
        const u64* __restrict__ rcur = (t & 1) ? buf1 : buf0;
        u64* __restrict__ rnxt = (t & 1) ? buf0 : buf1;

        // ---- input term prefetch (independent, overlaps poll) ----
        float extra = 0.f;
        if (tid < BSZ) {
            if (use_pre) {
                extra = pre[((size_t)t * HID + j) * BSZ + tid];
            } else {
                float isum = w_in_b[j];
                const float4* __restrict__ urow =
                    (const float4*)(u + ((size_t)tid * TLEN + t) * INW);
                const float4* __restrict__ wrow = (const float4*)(w_in_w + (size_t)j * INW);
#pragma unroll
                for (int q = 0; q < INW / 4; ++q) {
                    float4 uu = urow[q], ww = wrow[q];
                    isum = fmaf(uu.x, ww.x, isum);
                    isum = fmaf(uu.y, ww.y, isum);
                    isum = fmaf(uu.z, ww.z, isum);
                    isum = fmaf(uu.w, ww.w, isum);
                }
                float nz = noise[((size_t)t * BSZ + tid) * HID + j];
                extra = NOISE_STD * nz + TAU * isum;
            }
        }

        // ---- poll-load the 22 packets of column tid until tags == t ----
        u64 v[NPKT];
        {
            unsigned need = (1u << NPKT) - 1;
            while (need) {
#pragma unroll
                for (int c = 0; c < NPKT; ++c)
                    if (need & (1u << c))
                        v[c] = __hip_atomic_load(rcur + c * 256 + tid, __ATOMIC_RELAXED,
                                                 __HIP_MEMORY_SCOPE_AGENT);
#pragma unroll
                for (int c = 0; c < NPKT; ++c)
                    if ((need & (1u << c)) && (unsigned)(v[c] >> 48) == (unsigned)t)
                        need &= ~(1u << c);
                if (need) __builtin_amdgcn_s_sleep(1);
            }
        }
        __syncthreads();    // prev-step rlds/redw consumers done (WAR)

        // ---- fill rlds: thread = column k=tid, conflict-free b16 writes ----
#pragma unroll
        for (int c = 0; c < NPKT - 1; ++c)
#pragma unroll
            for (int e = 0; e < 3; ++e)
                rlds[ridx(3 * c + e, tid)] = (short)(v[c] >> (16 * e));
        rlds[ridx(63, tid)] = (short)v[NPKT - 1];
        __syncthreads();

        // ---- GEMM: P[b,i] = sum_k r[b,k] * W[j,i,k]  (B from VGPRs) ----
        floatx4 acc[4][4];
#pragma unroll
        for (int mb = 0; mb < 4; ++mb)
#pragma unroll
            for (int nj = 0; nj < 4; ++nj) acc[mb][nj] = (floatx4){0.f, 0.f, 0.f, 0.f};

#pragma unroll
        for (int kk = 0; kk < 8; ++kk) {
            short8 afrag[4];
#pragma unroll
            for (int mb = 0; mb < 4; ++mb)
                afrag[mb] = *(const short8*)&rlds[ridx(mb * 16 + col, kk * 32 + quad * 8)];
#pragma unroll
            for (int nj = 0; nj < 4; ++nj)
#pragma unroll
                for (int mb = 0; mb < 4; ++mb)
                    acc[mb][nj] = __builtin_amdgcn_mfma_f32_16x16x32_bf16(
                        afrag[mb], wreg[kk * 4 + nj], acc[mb][nj], 0, 0, 0);
        }

        // ---- epilogue: part[b] = sum_i r[b,i]*(P[b,i] + w_hh[j,i]) ----
        float part[16];
#pragma unroll
        for (int p = 0; p < 16; ++p) part[p] = 0.f;
#pragma unroll
        for (int nj = 0; nj < 4; ++nj) {
            int i = (w * 4 + nj) * 16 + col;
            float whh = whh_reg[nj];
#pragma unroll
            for (int mb = 0; mb < 4; ++mb)
#pragma unroll
                for (int reg = 0; reg < 4; ++reg) {
                    int b = mb * 16 + quad * 4 + reg;
                    short rs = rlds[ridx(b, i)];
                    float rv = __bfloat162float(*(__hip_bfloat16*)&rs);
                    part[mb * 4 + reg] = fmaf(rv, acc[mb][nj][reg] + whh, part[mb * 4 + reg]);
                }
        }
#pragma unroll
        for (int s = 1; s < 16; s <<= 1) {
#pragma unroll
            for (int p = 0; p < 16; ++p) part[p] += __shfl_xor(part[p], s, 64);
        }
        if (col == 0) {
#pragma unroll
            for (int mb = 0; mb < 4; ++mb)
#pragma unroll
                for (int reg = 0; reg < 4; ++reg)
                    redw[w * 64 + mb * 16 + quad * 4 + reg] = part[mb * 4 + reg];
        }
        __syncthreads();

        // ---- state update + publish (wave 0 only; one store instr, no drain) ----
        float xn = 0.f;
        if (tid < BSZ) {
            float rec = redw[tid] + redw[64 + tid] + redw[128 + tid] + redw[192 + tid];
            xn = xb + extra + TAU * (rec - xb);
            xb = xn;
            if (t < TLEN - 1) exch[tid] = __float2bfloat16(tanhf(xn));
        }
        if (t < TLEN - 1 && tid < NPKT) {      // same wave as exch writes: in-order
            int b0 = 3 * tid;
            u64 pv = (u64)(unsigned)(t + 1) << 48;
            pv |= (u64)(*(unsigned short*)&exch[b0]);
            if (b0 + 1 < BSZ) pv |= (u64)(*(unsigned short*)&exch[b0 + 1]) << 16;
            if (b0 + 2 < BSZ) pv |= (u64)(*(unsigned short*)&exch[b0 + 2]) << 32;
            __hip_atomic_store(rnxt + tid * 256 + j, pv, __ATOMIC_RELAXED,
                               __HIP_MEMORY_SCOPE_AGENT);
        }

        // ---- trajectory stores (off critical path) ----
        if (tid < BSZ) {
            if (use_tws) {
                trajWS[((size_t)t * HID + j) * BSZ + tid] = xn;   // 256B coalesced
            } else {
                traj[((size_t)tid * TLEN + t) * HID + j] = xn;
                if (t == TLEN - 1) xfinal[tid * HID + j] = xn;
            }
        }
    }
}

// ---------------------------------------------------------------------------
// fused transpose + output (fast path). block = t.
// ---------------------------------------------------------------------------
__global__ __launch_bounds__(256) void fixup_kernel(
    const float* __restrict__ trajWS,   // [T][HID][B]
    const float* __restrict__ w_out_w,  // [OUT][HID]
    const float* __restrict__ w_out_b,  // [OUT]
    float* __restrict__ traj,           // [B][T][HID]
    float* __restrict__ xfinal,         // [B][HID]
    float* __restrict__ out) {          // [B][T][OUT]
    __shared__ float xv[BSZ * 257];
    __shared__ float wol[OUTW * 257];
    const int t = blockIdx.x, tid = threadIdx.x;

#pragma unroll
    for (int it = 0; it < 16; ++it) {
        int flat = it * 1024 + tid * 4;          // j*64 + b
        float4 v = *(const float4*)(trajWS + (size_t)t * 16384 + flat);
        int jj = flat >> 6, b = flat & 63;
        xv[(b + 0) * 257 + jj] = v.x;
        xv[(b + 1) * 257 + jj] = v.y;
        xv[(b + 2) * 257 + jj] = v.z;
        xv[(b + 3) * 257 + jj] = v.w;
    }
#pragma unroll
    for (int it = 0; it < 8; ++it) {
        int flat = it * 1024 + tid * 4;          // o*256 + h
        float4 v = *(const float4*)(w_out_w + flat);
        int o = flat >> 8, h = flat & 255;
        *(float4*)&wol[o * 257 + h] = v;
    }
    __syncthreads();

    for (int b = 0; b < BSZ; ++b)
        traj[((size_t)b * TLEN + t) * HID + tid] = xv[b * 257 + tid];
    if (t == TLEN - 1)
        for (int b = 0; b < BSZ; ++b)
            xfinal[b * HID + tid] = xv[b * 257 + tid];

    __syncthreads();
#pragma unroll
    for (int it = 0; it < 64; ++it)
        xv[it * 257 + tid] = tanhf(xv[it * 257 + tid]);
    __syncthreads();

    const int o = tid & 31;
    const float bias = w_out_b[o];
#pragma unroll 1
    for (int rep = 0; rep < 8; ++rep) {
        int b = rep * 8 + (tid >> 5);
        float s = bias;
#pragma unroll 8
        for (int h = 0; h < HID; ++h)
            s = fmaf(xv[b * 257 + h], wol[o * 257 + h], s);
        out[((size_t)b * TLEN + t) * OUTW + o] = s;
    }
}

// ---------------------------------------------------------------------------
// fallback output kernel (reads traj from d_out) — used when ws too small
// ---------------------------------------------------------------------------
__global__ __launch_bounds__(256) void output_kernel(
    const float* __restrict__ traj, const float* __restrict__ w_out_w,
    const float* __restrict__ w_out_b, float* __restrict__ out) {
    __shared__ float th[8][HID + 1];
    const int bt0 = blockIdx.x * 8;
    const int tid = threadIdx.x;
#pragma unroll
    for (int m = 0; m < 8; ++m) {
        int idx = m * 256 + tid;
        th[idx >> 8][idx & 255] = tanhf(traj[(size_t)bt0 * HID + idx]);
    }
    __syncthreads();
    const int row = tid >> 5, o = tid & 31;
    const float* __restrict__ wrow = w_out_w + (size_t)o * HID;
    float s = w_out_b[o];
#pragma unroll 8
    for (int h = 0; h < HID; ++h) s = fmaf(th[row][h], wrow[h], s);
    out[(size_t)(bt0 + row) * OUTW + o] = s;
}

// ---------------------------------------------------------------------------
extern "C" void kernel_launch(void* const* d_in, const int* in_sizes, int n_in,
                              void* d_out, int out_size, void* d_ws, size_t ws_size,
                              hipStream_t stream) {
    const float* u       = (const float*)d_in[0];
    const float* x0      = (const float*)d_in[1];
    const float* noise   = (const float*)d_in[2];
    const float* w_hh    = (const float*)d_in[3];
    const float* W       = (const float*)d_in[4];
    const float* w_in_w  = (const float*)d_in[5];
    const float* w_in_b  = (const float*)d_in[6];
    const float* w_out_w = (const float*)d_in[7];
    const float* w_out_b = (const float*)d_in[8];

    float* out    = (float*)d_out;                     // [B][T][OUT]
    float* xfinal = out + (size_t)BSZ * TLEN * OUTW;
    float* traj   = xfinal + (size_t)BSZ * HID;

    // ws layout: Wsw 33.5M | buf0 45K | buf1 45K | trajWS 16.7M | pre 16.7M
    char* ws = (char*)d_ws;
    __hip_bfloat16* Wsw = (__hip_bfloat16*)ws;
    u64*   buf0 = (u64*)(ws + 33554432);
    u64*   buf1 = (u64*)(ws + 33599488);
    float* tws  = (float*)(ws + 33644544);
    float* pre  = (float*)(ws + 50421760);
    const size_t NEED_TWS = 50421760ull;
    const size_t NEED_PRE = 67198976ull;
    const int use_tws = (ws_size >= NEED_TWS) ? 1 : 0;
    const int use_pre = (ws_size >= NEED_PRE) ? 1 : 0;

    swizzle_kernel<<<8192, 256, 0, stream>>>(W, Wsw);
    init_kernel<<<NPKT, 256, 0, stream>>>(x0, buf0);
    if (use_pre)
        pre_kernel<<<TLEN, 256, 0, stream>>>(u, w_in_w, w_in_b, noise, pre);

    persist_kernel<<<256, 256, 0, stream>>>(
        Wsw, w_hh, u, w_in_w, w_in_b, noise, x0,
        buf0, buf1, traj, tws, xfinal, pre, use_pre, use_tws);

    if (use_tws)
        fixup_kernel<<<TLEN, 256, 0, stream>>>(tws, w_out_w, w_out_b, traj, xfinal, out);
    else
        output_kernel<<<(BSZ * TLEN) / 8, 256, 0, stream>>>(traj, w_out_w, w_out_b, out);
}

// Round 8
// 1610.779 us; speedup vs baseline: 1.7680x; 1.7680x over previous
//
#include <hip/hip_runtime.h>
#include <hip/hip_bf16.h>
#include <math.h>

#define HID 256
#define BSZ 64
#define TLEN 256
#define INW 64
#define OUTW 32
#define NOISE_STD 0.05f
#define TAU 0.2f

typedef __attribute__((ext_vector_type(8))) short short8;
typedef __attribute__((ext_vector_type(4))) float floatx4;
typedef unsigned long long u64;

// LDS layout for r: [b][k], 8-short-granule XOR swizzle.
// Fill (fixed b, lanes span k=tid): 32 banks, same-dword pairs merge -> free.
// A-frag b128 (8 consecutive k): uniform over bank groups -> minimum.
__device__ __forceinline__ int ridx(int b, int k) {
    int P = ((b >> 2) & 7) ^ ((b & 3) << 1);
    return b * 256 + ((((k >> 3) ^ P) & 31) << 3) + (k & 7);
}

// ---------------------------------------------------------------------------
// one-time: W [j][i][k] fp32 -> bf16 in MFMA B-fragment order
//   Wsw[(((j*8+kk)*16+ni)*64+l)*8 + e] = W[j][ni*16+(l&15)][kk*32+(l>>4)*8+e]
// ---------------------------------------------------------------------------
__global__ __launch_bounds__(256) void swizzle_kernel(const float* __restrict__ W,
                                                      __hip_bfloat16* __restrict__ Wsw) {
    int g = blockIdx.x * 256 + threadIdx.x;      // 0 .. 2^21-1
    int l  = g & 63;
    int ni = (g >> 6) & 15;
    int kk = (g >> 10) & 7;
    int j  = g >> 13;
    int i  = ni * 16 + (l & 15);
    int k0 = kk * 32 + (l >> 4) * 8;
    const float* __restrict__ src = W + ((size_t)j * HID + i) * HID + k0;
    __hip_bfloat16* __restrict__ dst = Wsw + (size_t)g * 8;
#pragma unroll
    for (int e = 0; e < 8; ++e) dst[e] = __float2bfloat16(src[e]);
}

// ---------------------------------------------------------------------------
// init: buf0[g*256+k] = pack4(bf16(tanh(x0[4g+e][k])))   (transposed packets)
// grid = 16 blocks (g), 256 threads (k)
// ---------------------------------------------------------------------------
__global__ __launch_bounds__(256) void init_kernel(const float* __restrict__ x0,
                                                   u64* __restrict__ buf0) {
    int g = blockIdx.x;          // 0..15
    int k = threadIdx.x;
    u64 v = 0;
#pragma unroll
    for (int e = 0; e < 4; ++e) {
        __hip_bfloat16 h = __float2bfloat16(tanhf(x0[(4 * g + e) * HID + k]));
        v |= (u64)(*(unsigned short*)&h) << (16 * e);
    }
    buf0[g * 256 + k] = v;
}

// ---------------------------------------------------------------------------
// one-time: pre[t][j][b] = NOISE_STD*noise[t][b][j]
//                        + TAU*(w_in_b[j] + sum_in u[b][t][in]*w_in_w[j][in])
// ---------------------------------------------------------------------------
__global__ __launch_bounds__(256) void pre_kernel(const float* __restrict__ u,
                                                  const float* __restrict__ w_in_w,
                                                  const float* __restrict__ w_in_b,
                                                  const float* __restrict__ noise,
                                                  float* __restrict__ pre) {
    __shared__ float ulds[BSZ][INW + 4];
    const int t = blockIdx.x;
    const int j = threadIdx.x;
    {
        int b = threadIdx.x >> 2, q = threadIdx.x & 3;
#pragma unroll
        for (int e = 0; e < 4; ++e) {
            float4 v = *(const float4*)(u + ((size_t)b * TLEN + t) * INW + q * 16 + e * 4);
            *(float4*)&ulds[b][q * 16 + e * 4] = v;
        }
    }
    float wreg[INW];
#pragma unroll
    for (int q = 0; q < INW / 4; ++q) {
        float4 v = *(const float4*)(w_in_w + (size_t)j * INW + q * 4);
        wreg[q * 4 + 0] = v.x; wreg[q * 4 + 1] = v.y;
        wreg[q * 4 + 2] = v.z; wreg[q * 4 + 3] = v.w;
    }
    float bias = w_in_b[j];
    __syncthreads();
    for (int b = 0; b < BSZ; ++b) {
        float s = bias;
#pragma unroll
        for (int in_ = 0; in_ < INW; ++in_) s = fmaf(ulds[b][in_], wreg[in_], s);
        float nz = noise[((size_t)t * BSZ + b) * HID + j];
        pre[((size_t)t * HID + j) * BSZ + b] = NOISE_STD * nz + TAU * s;
    }
}

// ---------------------------------------------------------------------------
// persistent kernel (R6 flag protocol + W-in-VGPR + transposed packets):
//  - state as [bgrp][k] u64 packets: consumer thread tid depends ONLY on
//    producer tid -> poll is thread-local (flag tid guards exactly the 16
//    u64s thread tid loads), fill is the conflict-free column pattern
//  - producer: shuffle-pack, 16 parallel stores, vmcnt(0) drain, flag store
//  - W B-fragments in 128 VGPRs/lane; 2 barriers/step; LDS padded ->1 blk/CU
// ---------------------------------------------------------------------------
__global__ __launch_bounds__(256, 1) void persist_kernel(
    const __hip_bfloat16* __restrict__ Wsw,
    const float* __restrict__ w_hh,
    const float* __restrict__ u,              // fallbacks
    const float* __restrict__ w_in_w,
    const float* __restrict__ w_in_b,
    const float* __restrict__ noise,
    const float* __restrict__ x0,
    u64* __restrict__ buf0,                   // [16][256] packets (t even reads)
    u64* __restrict__ buf1,                   // (t odd reads)
    float* __restrict__ traj,                 // [B][T][HID] (fallback path)
    float* __restrict__ trajWS,               // [T][HID][B] (fast path)
    float* __restrict__ xfinal,
    int* __restrict__ ready,                  // 256 flags, 64B apart (zeroed)
    const float* __restrict__ pre,            // [T][HID][B] or unused
    int use_pre, int use_tws) {
    __shared__ short rlds[16384];             // 32 KB swizzled r
    __shared__ float redw[256];
    __shared__ char lds_pad[57344];           // force 1 block/CU (total ~90 KB)

    const int tid  = threadIdx.x;
    const int j    = blockIdx.x;
    const int w    = tid >> 6;
    const int lane = tid & 63;
    const int quad = lane >> 4;
    const int col  = lane & 15;

    if (j == 0x7fffffff) lds_pad[tid] = 0;    // never true; keeps pad alive

    // ---- W B-fragments into registers: 32 x short8 = 128 VGPRs ----
    short8 wreg[32];
    {
        const short* __restrict__ wsh = (const short*)Wsw;
#pragma unroll
        for (int kk = 0; kk < 8; ++kk)
#pragma unroll
            for (int nj = 0; nj < 4; ++nj)
                wreg[kk * 4 + nj] = *(const short8*)(wsh +
                    ((((size_t)j * 8 + kk) * 16 + (w * 4 + nj)) * 64 + lane) * 8);
    }
    float whh_reg[4];
#pragma unroll
    for (int nj = 0; nj < 4; ++nj)
        whh_reg[nj] = w_hh[j * HID + (w * 4 + nj) * 16 + col];

    float xb = 0.f;
    if (tid < BSZ) xb = x0[tid * HID + j];

#pragma unroll 1
    for (int t = 0; t < TLEN; ++t) {
        const u64* __restrict__ rcur = (t & 1) ? buf1 : buf0;
        u64* __restrict__ rnxt = (t & 1) ? buf0 : buf1;

        // ---- input term prefetch (independent, overlaps poll) ----
        float extra = 0.f;
        if (tid < BSZ) {
            if (use_pre) {
                extra = pre[((size_t)t * HID + j) * BSZ + tid];
            } else {
                float isum = w_in_b[j];
                const float4* __restrict__ urow =
                    (const float4*)(u + ((size_t)tid * TLEN + t) * INW);
                const float4* __restrict__ wrow = (const float4*)(w_in_w + (size_t)j * INW);
#pragma unroll
                for (int q = 0; q < INW / 4; ++q) {
                    float4 uu = urow[q], ww = wrow[q];
                    isum = fmaf(uu.x, ww.x, isum);
                    isum = fmaf(uu.y, ww.y, isum);
                    isum = fmaf(uu.z, ww.z, isum);
                    isum = fmaf(uu.w, ww.w, isum);
                }
                float nz = noise[((size_t)t * BSZ + tid) * HID + j];
                extra = NOISE_STD * nz + TAU * isum;
            }
        }

        // ---- thread-local wait: flag tid guards exactly this thread's data ----
        if (t > 0) {
            while (__hip_atomic_load(ready + tid * 16, __ATOMIC_RELAXED,
                                     __HIP_MEMORY_SCOPE_AGENT) < t)
                __builtin_amdgcn_s_sleep(1);
            asm volatile("" ::: "memory");
        }

        // ---- load own column (producer tid's output), fill rlds ----
        {
            u64 v[16];
#pragma unroll
            for (int g = 0; g < 16; ++g)
                v[g] = __hip_atomic_load(rcur + g * 256 + tid, __ATOMIC_RELAXED,
                                         __HIP_MEMORY_SCOPE_AGENT);
#pragma unroll
            for (int g = 0; g < 16; ++g)
#pragma unroll
                for (int e = 0; e < 4; ++e)
                    rlds[ridx(4 * g + e, tid)] = (short)(v[g] >> (16 * e));
        }
        __syncthreads();                       // barrier B: rlds complete

        // ---- GEMM: P[b,i] = sum_k r[b,k] * W[j,i,k]  (B from VGPRs) ----
        floatx4 acc[4][4];
#pragma unroll
        for (int mb = 0; mb < 4; ++mb)
#pragma unroll
            for (int nj = 0; nj < 4; ++nj) acc[mb][nj] = (floatx4){0.f, 0.f, 0.f, 0.f};

#pragma unroll
        for (int kk = 0; kk < 8; ++kk) {
            short8 afrag[4];
#pragma unroll
            for (int mb = 0; mb < 4; ++mb)
                afrag[mb] = *(const short8*)&rlds[ridx(mb * 16 + col, kk * 32 + quad * 8)];
#pragma unroll
            for (int nj = 0; nj < 4; ++nj)
#pragma unroll
                for (int mb = 0; mb < 4; ++mb)
                    acc[mb][nj] = __builtin_amdgcn_mfma_f32_16x16x32_bf16(
                        afrag[mb], wreg[kk * 4 + nj], acc[mb][nj], 0, 0, 0);
        }

        // ---- epilogue: part[b] = sum_i r[b,i]*(P[b,i] + w_hh[j,i]) ----
        float part[16];
#pragma unroll
        for (int p = 0; p < 16; ++p) part[p] = 0.f;
#pragma unroll
        for (int nj = 0; nj < 4; ++nj) {
            int i = (w * 4 + nj) * 16 + col;
            float whh = whh_reg[nj];
#pragma unroll
            for (int mb = 0; mb < 4; ++mb)
#pragma unroll
                for (int reg = 0; reg < 4; ++reg) {
                    int b = mb * 16 + quad * 4 + reg;
                    short rs = rlds[ridx(b, i)];
                    float rv = __bfloat162float(*(__hip_bfloat16*)&rs);
                    part[mb * 4 + reg] = fmaf(rv, acc[mb][nj][reg] + whh, part[mb * 4 + reg]);
                }
        }
#pragma unroll
        for (int s = 1; s < 16; s <<= 1) {
#pragma unroll
            for (int p = 0; p < 16; ++p) part[p] += __shfl_xor(part[p], s, 64);
        }
        if (col == 0) {
#pragma unroll
            for (int mb = 0; mb < 4; ++mb)
#pragma unroll
                for (int reg = 0; reg < 4; ++reg)
                    redw[w * 64 + mb * 16 + quad * 4 + reg] = part[mb * 4 + reg];
        }
        __syncthreads();                       // barrier C: redw complete

        // ---- wave 0: state update, publish, trajectory ----
        if (w == 0) {
            const int b = lane;
            float rec = redw[b] + redw[64 + b] + redw[128 + b] + redw[192 + b];
            float xn = xb + extra + TAU * (rec - xb);
            xb = xn;

            if (t < TLEN - 1) {
                __hip_bfloat16 h = __float2bfloat16(tanhf(xn));
                int hs = (int)(*(unsigned short*)&h);
                int src = 4 * (lane & 15);
                u64 pv = (u64)(unsigned)__shfl(hs, src + 0, 64)
                       | ((u64)(unsigned)__shfl(hs, src + 1, 64) << 16)
                       | ((u64)(unsigned)__shfl(hs, src + 2, 64) << 32)
                       | ((u64)(unsigned)__shfl(hs, src + 3, 64) << 48);
                if (lane < 16)
                    __hip_atomic_store(rnxt + (size_t)lane * 256 + j, pv,
                                       __ATOMIC_RELAXED, __HIP_MEMORY_SCOPE_AGENT);
                asm volatile("s_waitcnt vmcnt(0)" ::: "memory");   // drain data
                if (lane == 0)
                    __hip_atomic_store(ready + j * 16, t + 1, __ATOMIC_RELAXED,
                                       __HIP_MEMORY_SCOPE_AGENT);
            }

            if (use_tws) {
                trajWS[((size_t)t * HID + j) * BSZ + b] = xn;      // 256B coalesced
            } else {
                traj[((size_t)b * TLEN + t) * HID + j] = xn;
                if (t == TLEN - 1) xfinal[b * HID + j] = xn;
            }
        }
    }
}

// ---------------------------------------------------------------------------
// fused transpose + output (fast path). block = t.
// ---------------------------------------------------------------------------
__global__ __launch_bounds__(256) void fixup_kernel(
    const float* __restrict__ trajWS,   // [T][HID][B]
    const float* __restrict__ w_out_w,  // [OUT][HID]
    const float* __restrict__ w_out_b,  // [OUT]
    float* __restrict__ traj,           // [B][T][HID]
    float* __restrict__ xfinal,         // [B][HID]
    float* __restrict__ out) {          // [B][T][OUT]
    __shared__ float xv[BSZ * 257];
    __shared__ float wol[OUTW * 257];
    const int t = blockIdx.x, tid = threadIdx.x;

#pragma unroll
    for (int it = 0; it < 16; ++it) {
        int flat = it * 1024 + tid * 4;          // j*64 + b
        float4 v = *(const float4*)(trajWS + (size_t)t * 16384 + flat);
        int jj = flat >> 6, b = flat & 63;
        xv[(b + 0) * 257 + jj] = v.x;
        xv[(b + 1) * 257 + jj] = v.y;
        xv[(b + 2) * 257 + jj] = v.z;
        xv[(b + 3) * 257 + jj] = v.w;
    }
#pragma unroll
    for (int it = 0; it < 8; ++it) {
        int flat = it * 1024 + tid * 4;          // o*256 + h
        float4 v = *(const float4*)(w_out_w + flat);
        int o = flat >> 8, h = flat & 255;
        *(float4*)&wol[o * 257 + h] = v;
    }
    __syncthreads();

    for (int b = 0; b < BSZ; ++b)
        traj[((size_t)b * TLEN + t) * HID + tid] = xv[b * 257 + tid];
    if (t == TLEN - 1)
        for (int b = 0; b < BSZ; ++b)
            xfinal[b * HID + tid] = xv[b * 257 + tid];

    __syncthreads();
#pragma unroll
    for (int it = 0; it < 64; ++it)
        xv[it * 257 + tid] = tanhf(xv[it * 257 + tid]);
    __syncthreads();

    const int o = tid & 31;
    const float bias = w_out_b[o];
#pragma unroll 1
    for (int rep = 0; rep < 8; ++rep) {
        int b = rep * 8 + (tid >> 5);
        float s = bias;
#pragma unroll 8
        for (int h = 0; h < HID; ++h)
            s = fmaf(xv[b * 257 + h], wol[o * 257 + h], s);
        out[((size_t)b * TLEN + t) * OUTW + o] = s;
    }
}

// ---------------------------------------------------------------------------
// fallback output kernel — used when ws too small
// ---------------------------------------------------------------------------
__global__ __launch_bounds__(256) void output_kernel(
    const float* __restrict__ traj, const float* __restrict__ w_out_w,
    const float* __restrict__ w_out_b, float* __restrict__ out) {
    __shared__ float th[8][HID + 1];
    const int bt0 = blockIdx.x * 8;
    const int tid = threadIdx.x;
#pragma unroll
    for (int m = 0; m < 8; ++m) {
        int idx = m * 256 + tid;
        th[idx >> 8][idx & 255] = tanhf(traj[(size_t)bt0 * HID + idx]);
    }
    __syncthreads();
    const int row = tid >> 5, o = tid & 31;
    const float* __restrict__ wrow = w_out_w + (size_t)o * HID;
    float s = w_out_b[o];
#pragma unroll 8
    for (int h = 0; h < HID; ++h) s = fmaf(th[row][h], wrow[h], s);
    out[(size_t)(bt0 + row) * OUTW + o] = s;
}

// ---------------------------------------------------------------------------
extern "C" void kernel_launch(void* const* d_in, const int* in_sizes, int n_in,
                              void* d_out, int out_size, void* d_ws, size_t ws_size,
                              hipStream_t stream) {
    const float* u       = (const float*)d_in[0];
    const float* x0      = (const float*)d_in[1];
    const float* noise   = (const float*)d_in[2];
    const float* w_hh    = (const float*)d_in[3];
    const float* W       = (const float*)d_in[4];
    const float* w_in_w  = (const float*)d_in[5];
    const float* w_in_b  = (const float*)d_in[6];
    const float* w_out_w = (const float*)d_in[7];
    const float* w_out_b = (const float*)d_in[8];

    float* out    = (float*)d_out;                     // [B][T][OUT]
    float* xfinal = out + (size_t)BSZ * TLEN * OUTW;
    float* traj   = xfinal + (size_t)BSZ * HID;

    // ws layout: Wsw 33.5M | buf0 32K | buf1 32K | flags 16K | trajWS 16.7M | pre 16.7M
    char* ws = (char*)d_ws;
    __hip_bfloat16* Wsw = (__hip_bfloat16*)ws;
    u64*   buf0 = (u64*)(ws + 33554432);
    u64*   buf1 = (u64*)(ws + 33587200);
    int*   rdy  = (int*)(ws + 33619968);
    float* tws  = (float*)(ws + 33636352);
    float* pre  = (float*)(ws + 50413568);
    const size_t NEED_TWS = 50413568ull;
    const size_t NEED_PRE = 67190784ull;
    const int use_tws = (ws_size >= NEED_TWS) ? 1 : 0;
    const int use_pre = (ws_size >= NEED_PRE) ? 1 : 0;

    hipMemsetAsync(rdy, 0, 16384, stream);
    swizzle_kernel<<<8192, 256, 0, stream>>>(W, Wsw);
    init_kernel<<<16, 256, 0, stream>>>(x0, buf0);
    if (use_pre)
        pre_kernel<<<TLEN, 256, 0, stream>>>(u, w_in_w, w_in_b, noise, pre);

    persist_kernel<<<256, 256, 0, stream>>>(
        Wsw, w_hh, u, w_in_w, w_in_b, noise, x0,
        buf0, buf1, traj, tws, xfinal, rdy, pre, use_pre, use_tws);

    if (use_tws)
        fixup_kernel<<<TLEN, 256, 0, stream>>>(tws, w_out_w, w_out_b, traj, xfinal, out);
    else
        output_kernel<<<(BSZ * TLEN) / 8, 256, 0, stream>>>(traj, w_out_w, w_out_b, out);
}